// Round 1
// baseline (471.178 us; speedup 1.0000x reference)
//
#include <hip/hip_runtime.h>
#include <stdint.h>

// Problem constants (fixed by reference)
#define BB    16
#define NN    1000
#define DD    2048
#define KK    256
#define SIG   0.05f
#define INVN  (1.0f / 1000.0f)

#define BDIM  256
#define NBUCK 4096   // 12-bit high-bits histogram

// One block = one (b,n) row.
// Algorithm: ordered-uint keys -> 4096-bucket histogram -> suffix counts F(b)
// -> candidate compaction (buckets with F(b+1) < K) grouped by bucket
// -> exact rank = F(b+1) + within-bucket count -> atomicAdd(out[b,rank,d], 1/N).
__global__ __launch_bounds__(BDIM) void ptopk_kernel(
    const float* __restrict__ x,
    const float* __restrict__ noise,
    float* __restrict__ out)
{
    __shared__ uint32_t sF[NBUCK + 1];          // histogram, then F(b) suffix counts
    __shared__ uint32_t sCur[NBUCK];            // per-bucket compaction cursors
    __shared__ uint32_t sCS[BDIM];              // chunk sums for suffix scan
    __shared__ unsigned long long sCand[DD];    // candidate keys, bucket-grouped desc
    __shared__ uint32_t sC;                     // total candidate count

    const int t   = threadIdx.x;
    const int row = blockIdx.x;                 // = b*NN + n
    const int b   = row / NN;

    // ---- init histogram + cursors ----
    #pragma unroll
    for (int i = 0; i < NBUCK / BDIM; ++i) {
        sF[t + i * BDIM]   = 0u;
        sCur[t + i * BDIM] = 0u;
    }
    if (t == 0) sF[NBUCK] = 0u;                 // F(4096) = 0, never touched again
    __syncthreads();

    // ---- load row, build ordered keys, histogram ----
    const float4* nrow = (const float4*)(noise + (size_t)row * DD);
    const float4* xrow = (const float4*)(x + (size_t)b * DD);

    float4 n0 = nrow[t];
    float4 n1 = nrow[t + BDIM];
    float4 x0 = xrow[t];
    float4 x1 = xrow[t + BDIM];

    float v[8];
    // match numpy exactly: separate round of mul and add (no FMA contraction)
    v[0] = __fadd_rn(x0.x, __fmul_rn(n0.x, SIG));
    v[1] = __fadd_rn(x0.y, __fmul_rn(n0.y, SIG));
    v[2] = __fadd_rn(x0.z, __fmul_rn(n0.z, SIG));
    v[3] = __fadd_rn(x0.w, __fmul_rn(n0.w, SIG));
    v[4] = __fadd_rn(x1.x, __fmul_rn(n1.x, SIG));
    v[5] = __fadd_rn(x1.y, __fmul_rn(n1.y, SIG));
    v[6] = __fadd_rn(x1.z, __fmul_rn(n1.z, SIG));
    v[7] = __fadd_rn(x1.w, __fmul_rn(n1.w, SIG));

    uint32_t u[8];
    #pragma unroll
    for (int i = 0; i < 8; ++i) {
        uint32_t ub = __float_as_uint(v[i]);
        u[i] = (ub & 0x80000000u) ? ~ub : (ub | 0x80000000u);  // order-preserving
        atomicAdd(&sF[u[i] >> 20], 1u);
    }
    __syncthreads();

    // ---- suffix counts F(b) = #elements in buckets >= b ----
    // chunk sums (16 buckets per thread)
    uint32_t csum = 0;
    #pragma unroll
    for (int i = 0; i < 16; ++i) csum += sF[t * 16 + i];
    sCS[t] = csum;
    __syncthreads();

    // Hillis-Steele inclusive suffix scan over 256 chunk sums
    uint32_t val = csum;
    for (int ofs = 1; ofs < BDIM; ofs <<= 1) {
        uint32_t add = (t + ofs < BDIM) ? sCS[t + ofs] : 0u;
        __syncthreads();
        val += add;
        sCS[t] = val;
        __syncthreads();
    }

    // in-place per-chunk suffix: sF[b] <- F(b)
    uint32_t running = (t == BDIM - 1) ? 0u : sCS[t + 1];
    #pragma unroll
    for (int i = 15; i >= 0; --i) {
        int bk = t * 16 + i;
        uint32_t h = sF[bk];
        running += h;
        sF[bk] = running;
    }
    __syncthreads();

    // ---- find total candidate count C = F(b*) at the unique crossing bucket ----
    #pragma unroll
    for (int i = 0; i < 16; ++i) {
        int bk = t * 16 + i;
        if (sF[bk] >= KK && sF[bk + 1] < KK) sC = sF[bk];
    }

    // ---- compact candidates, grouped by bucket (desc) ----
    // key: high 32 bits = ordered value, low 16 = (2047-d) so ties rank lower d first
    #pragma unroll
    for (int i = 0; i < 8; ++i) {
        uint32_t ui = u[i];
        int bk = (int)(ui >> 20);
        if (sF[bk + 1] < KK) {                  // bucket can contain top-K members
            uint32_t pos = sF[bk + 1] + atomicAdd(&sCur[bk], 1u);
            int d = (i < 4) ? (4 * t + i) : (1024 + 4 * t + (i - 4));
            sCand[pos] = ((unsigned long long)ui << 16) |
                         (unsigned long long)(DD - 1 - d);
        }
    }
    __syncthreads();

    // ---- exact rank within candidate set; scatter ----
    const int C = (int)sC;
    for (int p = t; p < C; p += BDIM) {
        unsigned long long key = sCand[p];
        int bk  = (int)(key >> 36);             // bucket = ordered-uint >> 20
        int lo  = (int)sF[bk + 1];              // elements strictly above this bucket
        int hi  = (int)sF[bk];
        int rank = lo;
        for (int j = lo; j < hi; ++j)
            rank += (sCand[j] > key) ? 1 : 0;
        if (rank < KK) {
            int d = DD - 1 - (int)(key & 0xFFFFull);
            atomicAdd(&out[((size_t)b * KK + rank) * DD + d], INVN);
        }
    }
}

extern "C" void kernel_launch(void* const* d_in, const int* in_sizes, int n_in,
                              void* d_out, int out_size, void* d_ws, size_t ws_size,
                              hipStream_t stream) {
    const float* x     = (const float*)d_in[0];
    const float* noise = (const float*)d_in[1];
    float* out         = (float*)d_out;

    // output is sparse-scattered: must zero it first (d_out is poisoned 0xAA)
    hipMemsetAsync(out, 0, (size_t)out_size * sizeof(float), stream);

    hipLaunchKernelGGL(ptopk_kernel,
                       dim3(BB * NN), dim3(BDIM), 0, stream,
                       x, noise, out);
}

// Round 2
// 349.202 us; speedup vs baseline: 1.3493x; 1.3493x over previous
//
#include <hip/hip_runtime.h>
#include <stdint.h>

// Problem constants (fixed by reference)
#define BB    16
#define NN    1000
#define DD    2048
#define KK    256
#define SIG   0.05f
#define INVN  (1.0f / 1000.0f)

#define T1    1024
#define NBUCK 4096   // 12-bit high-bits histogram

// ---------------- Kernel 1: per-row exact top-K ranks -> uint16 index list --
// One block = one (b,n) row, 1024 threads x 2 elements.
// ordered-uint keys -> 4096-bucket histogram -> suffix counts F(b) via
// shuffle scan (2 barriers) -> candidate compaction -> exact rank ->
// idxws[row][rank] = d  (coalesced uint4 store).
__global__ __launch_bounds__(T1, 8) void ptopk_rank(
    const float* __restrict__ x,
    const float* __restrict__ noise,
    uint16_t* __restrict__ idxws)
{
    __shared__ __align__(16) uint32_t sF[NBUCK + 4];   // hist -> F(b) suffix counts
    __shared__ __align__(16) uint32_t sCur[NBUCK];     // per-bucket compaction cursors
    __shared__ uint32_t sWS[16];                       // per-wave totals
    __shared__ unsigned long long sCand[DD];           // candidates, bucket-grouped
    __shared__ __align__(16) uint16_t sIdx[KK];        // rank -> d
    __shared__ uint32_t sC;                            // candidate count

    const int t    = threadIdx.x;
    const int lane = t & 63;
    const int w    = t >> 6;
    const int row  = blockIdx.x;
    const int b    = row / NN;

    // ---- vectorized init (1 uint4 store per array per thread) ----
    uint4 z; z.x = z.y = z.z = z.w = 0u;
    ((uint4*)sF)[t]   = z;
    ((uint4*)sCur)[t] = z;
    if (t == 0) { sF[NBUCK] = 0u; }
    __syncthreads();

    // ---- load 2 elements, ordered keys, histogram ----
    const float2* nrow = (const float2*)(noise + (size_t)row * DD);
    const float2* xrow = (const float2*)(x + (size_t)b * DD);
    float2 nv = nrow[t];
    float2 xv = xrow[t];
    // match numpy: separate rounded mul and add (no FMA contraction)
    float v0 = __fadd_rn(xv.x, __fmul_rn(nv.x, SIG));
    float v1 = __fadd_rn(xv.y, __fmul_rn(nv.y, SIG));
    uint32_t ub0 = __float_as_uint(v0);
    uint32_t ub1 = __float_as_uint(v1);
    uint32_t u0 = (ub0 & 0x80000000u) ? ~ub0 : (ub0 | 0x80000000u);
    uint32_t u1 = (ub1 & 0x80000000u) ? ~ub1 : (ub1 | 0x80000000u);
    const int d0 = 2 * t, d1 = 2 * t + 1;
    atomicAdd(&sF[u0 >> 20], 1u);
    atomicAdd(&sF[u1 >> 20], 1u);
    __syncthreads();

    // ---- suffix counts F(b): thread owns buckets [4t, 4t+4) ----
    const int b0 = 4 * t;
    uint32_t h0 = sF[b0], h1 = sF[b0 + 1], h2 = sF[b0 + 2], h3 = sF[b0 + 3];
    uint32_t csum = h0 + h1 + h2 + h3;

    // wave-level inclusive suffix scan (higher lane = higher buckets)
    uint32_t s = csum;
    #pragma unroll
    for (int ofs = 1; ofs < 64; ofs <<= 1) {
        uint32_t o = __shfl_down(s, ofs, 64);
        s += (lane + ofs < 64) ? o : 0u;
    }
    if (lane == 0) sWS[w] = s;   // wave total
    __syncthreads();
    if (t == 0) {                 // exclusive suffix over 16 wave totals
        uint32_t run = 0;
        #pragma unroll
        for (int i = 15; i >= 0; --i) { uint32_t tmp = sWS[i]; sWS[i] = run; run += tmp; }
    }
    __syncthreads();

    uint32_t above = sWS[w] + (s - csum);   // sum of all buckets > 4t+3
    uint32_t F3 = above + h3;
    uint32_t F2 = F3 + h2;
    uint32_t F1 = F2 + h1;
    uint32_t F0 = F1 + h0;
    sF[b0]     = F0;
    sF[b0 + 1] = F1;
    sF[b0 + 2] = F2;
    sF[b0 + 3] = F3;
    __syncthreads();

    // ---- crossing bucket: F(bk) >= K > F(bk+1) -> C = F(bk) ----
    uint32_t Fn = sF[b0 + 4];                 // t==1023 reads sF[4096]==0
    if (F0 >= KK && F1 < KK) sC = F0;
    if (F1 >= KK && F2 < KK) sC = F1;
    if (F2 >= KK && F3 < KK) sC = F2;
    if (F3 >= KK && Fn < KK) sC = F3;

    // ---- compact candidates, grouped by bucket ----
    // key: high 32 = ordered value, low 16 = (2047-d) so ties rank lower d first
    {
        int bk = (int)(u0 >> 20);
        uint32_t fn = sF[bk + 1];
        if (fn < KK) {
            uint32_t pos = fn + atomicAdd(&sCur[bk], 1u);
            sCand[pos] = ((unsigned long long)u0 << 16) |
                         (unsigned long long)(DD - 1 - d0);
        }
        bk = (int)(u1 >> 20);
        fn = sF[bk + 1];
        if (fn < KK) {
            uint32_t pos = fn + atomicAdd(&sCur[bk], 1u);
            sCand[pos] = ((unsigned long long)u1 << 16) |
                         (unsigned long long)(DD - 1 - d1);
        }
    }
    __syncthreads();

    // ---- exact rank within candidate set ----
    const int C = (int)sC;
    for (int p = t; p < C; p += T1) {
        unsigned long long key = sCand[p];
        int bk = (int)(key >> 36);
        int lo = (int)sF[bk + 1];
        int hi = (int)sF[bk];
        int rank = lo;
        for (int j = lo; j < hi; ++j)
            rank += (sCand[j] > key) ? 1 : 0;
        if (rank < KK)
            sIdx[rank] = (uint16_t)(DD - 1 - (int)(key & 0xFFFFull));
    }
    __syncthreads();

    // ---- coalesced write of the 256 uint16 indices (512B = 32 x uint4) ----
    if (t < 32) {
        uint4 vv = ((const uint4*)sIdx)[t];
        ((uint4*)(idxws + (size_t)row * KK))[t] = vv;
    }
}

// ---------------- Kernel 2: accumulate indicators, dense write, no atomics --
// One block = (b, group of 16 ranks). LDS holds 16 x 2048 packed uint16
// counters (as uint32 pairs). Reads 1000 n-contributions, histograms, writes
// out[b][k][d] = count/N densely (no memset, no global atomics, no RMW).
#define T2 256
__global__ __launch_bounds__(T2) void ptopk_accum(
    const uint16_t* __restrict__ idxws,
    float* __restrict__ out)
{
    __shared__ __align__(16) uint32_t hist[16 * 1024];   // 64 KB

    const int t  = threadIdx.x;
    const int b  = blockIdx.x >> 4;
    const int kg = blockIdx.x & 15;

    uint4 z; z.x = z.y = z.z = z.w = 0u;
    #pragma unroll
    for (int i = 0; i < 16; ++i)
        ((uint4*)hist)[i * T2 + t] = z;
    __syncthreads();

    const int k = t & 15;
    const uint16_t* base = idxws + (size_t)b * NN * KK + kg * 16 + k;
    for (int n = t >> 4; n < NN; n += 16) {
        int d = (int)base[(size_t)n * KK];
        atomicAdd(&hist[(k << 10) + (d >> 1)], 1u << ((d & 1) << 4));
    }
    __syncthreads();

    // dense coalesced write: 16 k-rows x 2048 floats
    float2* out2 = (float2*)(out + ((size_t)(b * KK + kg * 16) << 11));
    #pragma unroll
    for (int i = 0; i < 64; ++i) {
        int j = i * T2 + t;                  // j = k'*1024 + dpair
        uint32_t wv = hist[j];
        float2 f;
        f.x = (float)(wv & 0xFFFFu) * INVN;
        f.y = (float)(wv >> 16)     * INVN;
        out2[j] = f;
    }
}

extern "C" void kernel_launch(void* const* d_in, const int* in_sizes, int n_in,
                              void* d_out, int out_size, void* d_ws, size_t ws_size,
                              hipStream_t stream) {
    const float* x     = (const float*)d_in[0];
    const float* noise = (const float*)d_in[1];
    float* out         = (float*)d_out;
    uint16_t* idxws    = (uint16_t*)d_ws;    // needs BB*NN*KK*2 = 8.2 MB

    hipLaunchKernelGGL(ptopk_rank,
                       dim3(BB * NN), dim3(T1), 0, stream,
                       x, noise, idxws);
    hipLaunchKernelGGL(ptopk_accum,
                       dim3(BB * (KK / 16)), dim3(T2), 0, stream,
                       idxws, out);
}

// Round 3
// 270.412 us; speedup vs baseline: 1.7424x; 1.2914x over previous
//
#include <hip/hip_runtime.h>
#include <stdint.h>

// Problem constants (fixed by reference)
#define BB    16
#define NN    1000
#define DD    2048
#define KK    256
#define SIG   0.05f
#define INVN  (1.0f / 1000.0f)

#define T1    512
#define NBUCK 4096   // 12-bit high-bits histogram

// ---------------- Kernel 1: per-row exact top-K ranks -> uint16 index list --
// One block = one (b,n) row, 512 threads x 4 elements. ~33 KB LDS ->
// 4 blocks/CU (32 waves, full occupancy).
// ordered-uint keys -> 4096-bucket histogram -> suffix counts F(b) ->
// compaction directly into sF cursors (atomicAdd on sF[bk+1] allocates slots
// and leaves sF[bk+1]==F(bk)) -> exact rank -> idxws[row][rank] = d.
__global__ __launch_bounds__(T1, 8) void ptopk_rank(
    const float* __restrict__ x,
    const float* __restrict__ noise,
    uint16_t* __restrict__ idxws)
{
    __shared__ __align__(16) uint32_t sF[NBUCK + 8];   // hist -> F(b); [4096..]=0
    __shared__ uint32_t sWS[8];                        // per-wave totals
    __shared__ unsigned long long sCand[DD];           // candidates, bucket-grouped
    __shared__ __align__(16) uint16_t sIdx[KK];        // rank -> d
    __shared__ uint32_t sC;                            // candidate count

    const int t    = threadIdx.x;
    const int lane = t & 63;
    const int w    = t >> 6;
    const int row  = blockIdx.x;
    const int b    = row / NN;

    // ---- vectorized init: 4104 words = 1026 uint4 ----
    uint4 z; z.x = z.y = z.z = z.w = 0u;
    ((uint4*)sF)[t]       = z;
    ((uint4*)sF)[t + T1]  = z;
    if (t < 2) ((uint4*)sF)[1024 + t] = z;
    __syncthreads();

    // ---- load 4 elements, ordered keys, histogram ----
    const float4* nrow = (const float4*)(noise + (size_t)row * DD);
    const float4* xrow = (const float4*)(x + (size_t)b * DD);
    float4 nv = nrow[t];
    float4 xv = xrow[t];
    // match numpy: separate rounded mul and add (no FMA contraction)
    float v0 = __fadd_rn(xv.x, __fmul_rn(nv.x, SIG));
    float v1 = __fadd_rn(xv.y, __fmul_rn(nv.y, SIG));
    float v2 = __fadd_rn(xv.z, __fmul_rn(nv.z, SIG));
    float v3 = __fadd_rn(xv.w, __fmul_rn(nv.w, SIG));
    uint32_t u[4];
    {
        uint32_t ub;
        ub = __float_as_uint(v0); u[0] = (ub & 0x80000000u) ? ~ub : (ub | 0x80000000u);
        ub = __float_as_uint(v1); u[1] = (ub & 0x80000000u) ? ~ub : (ub | 0x80000000u);
        ub = __float_as_uint(v2); u[2] = (ub & 0x80000000u) ? ~ub : (ub | 0x80000000u);
        ub = __float_as_uint(v3); u[3] = (ub & 0x80000000u) ? ~ub : (ub | 0x80000000u);
    }
    #pragma unroll
    for (int i = 0; i < 4; ++i) atomicAdd(&sF[u[i] >> 20], 1u);
    __syncthreads();

    // ---- suffix counts F(b): thread owns buckets [8t, 8t+8) ----
    const int b0 = 8 * t;
    uint4 ha = ((const uint4*)sF)[2 * t];
    uint4 hb = ((const uint4*)sF)[2 * t + 1];
    uint32_t h[8] = { ha.x, ha.y, ha.z, ha.w, hb.x, hb.y, hb.z, hb.w };
    uint32_t csum = h[0] + h[1] + h[2] + h[3] + h[4] + h[5] + h[6] + h[7];

    // wave-level inclusive suffix scan (higher lane = higher buckets)
    uint32_t s = csum;
    #pragma unroll
    for (int ofs = 1; ofs < 64; ofs <<= 1) {
        uint32_t o = __shfl_down(s, ofs, 64);
        s += (lane + ofs < 64) ? o : 0u;
    }
    if (lane == 0) sWS[w] = s;
    __syncthreads();
    if (t == 0) {                 // exclusive suffix over 8 wave totals
        uint32_t run = 0;
        #pragma unroll
        for (int i = 7; i >= 0; --i) { uint32_t tmp = sWS[i]; sWS[i] = run; run += tmp; }
    }
    __syncthreads();

    uint32_t above = sWS[w] + (s - csum);       // F(8t+8)
    uint32_t F[9];
    F[8] = above;
    #pragma unroll
    for (int i = 7; i >= 0; --i) F[i] = F[i + 1] + h[i];

    uint4 fa, fb;
    fa.x = F[0]; fa.y = F[1]; fa.z = F[2]; fa.w = F[3];
    fb.x = F[4]; fb.y = F[5]; fb.z = F[6]; fb.w = F[7];
    ((uint4*)sF)[2 * t]     = fa;
    ((uint4*)sF)[2 * t + 1] = fb;

    // crossing bucket: F(bk) >= K > F(bk+1)  ->  C = F(bk)
    #pragma unroll
    for (int i = 0; i < 8; ++i)
        if (F[i] >= KK && F[i + 1] < KK) sC = F[i];
    __syncthreads();

    // ---- candidacy snapshot (clean read of F before atomics mutate sF) ----
    int  bk[4];
    bool cand[4];
    #pragma unroll
    for (int i = 0; i < 4; ++i) {
        bk[i]   = (int)(u[i] >> 20);
        cand[i] = sF[bk[i] + 1] < KK;
    }
    __syncthreads();

    // ---- compact candidates; atomicAdd on sF[bk+1] allocates slots and
    //      leaves sF[bk+1] == F(bk) for every candidate bucket ----
    // key: high 32 = ordered value, low 16 = (2047-d) so ties rank lower d first
    #pragma unroll
    for (int i = 0; i < 4; ++i) {
        if (cand[i]) {
            uint32_t pos = atomicAdd(&sF[bk[i] + 1], 1u);
            int d = 4 * t + i;
            sCand[pos] = ((unsigned long long)u[i] << 16) |
                         (unsigned long long)(DD - 1 - d);
        }
    }
    __syncthreads();

    // ---- exact rank within candidate set ----
    // post-compaction: sF[bk+1] = F(bk) (hi), sF[bk+2] = F(bk+1) (lo)
    const int C = (int)sC;
    for (int p = t; p < C; p += T1) {
        unsigned long long key = sCand[p];
        int bkk = (int)(key >> 36);
        int hi  = (int)sF[bkk + 1];
        int lo  = (int)sF[bkk + 2];
        int rank = lo;
        for (int j = lo; j < hi; ++j)
            rank += (sCand[j] > key) ? 1 : 0;
        if (rank < KK)
            sIdx[rank] = (uint16_t)(DD - 1 - (int)(key & 0xFFFFull));
    }
    __syncthreads();

    // ---- coalesced write of the 256 uint16 indices (512B = 32 x uint4) ----
    if (t < 32) {
        uint4 vv = ((const uint4*)sIdx)[t];
        ((uint4*)(idxws + (size_t)row * KK))[t] = vv;
    }
}

// ---------------- Kernel 2: accumulate indicators, dense write, no atomics --
// One block = one (b,k) pair: 4096 blocks x 256 threads, 4 KB LDS histogram.
// Reads 1000 uint16 (L2-resident, strided), histograms into packed uint16
// pairs, writes out[b][k][:] densely (no memset, no global atomics).
#define T2 256
__global__ __launch_bounds__(T2) void ptopk_accum(
    const uint16_t* __restrict__ idxws,
    float* __restrict__ out)
{
    __shared__ __align__(16) uint32_t hist[DD / 2];   // 1024 words = 4 KB

    const int t   = threadIdx.x;
    const int bkx = blockIdx.x;          // = b*KK + k
    const int b   = bkx >> 8;
    const int k   = bkx & 255;

    uint4 z; z.x = z.y = z.z = z.w = 0u;
    ((uint4*)hist)[t] = z;
    __syncthreads();

    const uint16_t* base = idxws + (size_t)b * NN * KK + k;
    for (int n = t; n < NN; n += T2) {
        int d = (int)base[(size_t)n * KK];
        atomicAdd(&hist[d >> 1], 1u << ((d & 1) << 4));
    }
    __syncthreads();

    // dense coalesced write: 2048 floats (each thread: 8 counts -> 2 float4)
    float4* out4 = (float4*)(out + (size_t)bkx * DD);
    uint4 wv = ((const uint4*)hist)[t];
    float4 f0, f1;
    f0.x = (float)(wv.x & 0xFFFFu) * INVN;  f0.y = (float)(wv.x >> 16) * INVN;
    f0.z = (float)(wv.y & 0xFFFFu) * INVN;  f0.w = (float)(wv.y >> 16) * INVN;
    f1.x = (float)(wv.z & 0xFFFFu) * INVN;  f1.y = (float)(wv.z >> 16) * INVN;
    f1.z = (float)(wv.w & 0xFFFFu) * INVN;  f1.w = (float)(wv.w >> 16) * INVN;
    out4[2 * t]     = f0;
    out4[2 * t + 1] = f1;
}

extern "C" void kernel_launch(void* const* d_in, const int* in_sizes, int n_in,
                              void* d_out, int out_size, void* d_ws, size_t ws_size,
                              hipStream_t stream) {
    const float* x     = (const float*)d_in[0];
    const float* noise = (const float*)d_in[1];
    float* out         = (float*)d_out;
    uint16_t* idxws    = (uint16_t*)d_ws;    // needs BB*NN*KK*2 = 8.2 MB

    hipLaunchKernelGGL(ptopk_rank,
                       dim3(BB * NN), dim3(T1), 0, stream,
                       x, noise, idxws);
    hipLaunchKernelGGL(ptopk_accum,
                       dim3(BB * KK), dim3(T2), 0, stream,
                       idxws, out);
}

// Round 4
// 263.088 us; speedup vs baseline: 1.7909x; 1.0278x over previous
//
#include <hip/hip_runtime.h>
#include <stdint.h>

// Problem constants (fixed by reference)
#define BB    16
#define NN    1000
#define DD    2048
#define KK    256
#define SIG   0.05f
#define INVN  (1.0f / 1000.0f)

#define T1    512
#define NBUCK 4096   // 12-bit high-bits histogram

// ---------------- Kernel 1: per-row exact top-K ranks -> transposed uint16 --
// One block = one (b,n) row, 512 threads x 4 elements, ~33 KB LDS ->
// 4 blocks/CU (32 waves = occupancy cap).
// ordered-uint keys -> 4096-bucket histogram -> suffix counts F(b) ->
// crossing bucket b* (rank-K boundary) -> compaction into sF cursors
// (atomicAdd on sF[bk+1]; candidacy is just bucket >= b*) -> exact rank ->
// scattered store idxT[b][rank][n] = d (2B stores; K2 then reads coalesced).
__global__ __launch_bounds__(T1, 8) void ptopk_rank(
    const float* __restrict__ x,
    const float* __restrict__ noise,
    uint16_t* __restrict__ idxT)
{
    __shared__ __align__(16) uint32_t sF[NBUCK + 8];   // hist -> F(b); [4096..]=0
    __shared__ uint32_t sWS[8];                        // per-wave totals
    __shared__ unsigned long long sCand[DD];           // candidates, bucket-grouped
    __shared__ uint16_t sIdx[KK];                      // rank -> d
    __shared__ uint32_t sC;                            // candidate count
    __shared__ uint32_t sBstar;                        // crossing bucket

    const int t    = threadIdx.x;
    const int lane = t & 63;
    const int w    = t >> 6;
    const int row  = blockIdx.x;
    const int b    = row / NN;
    const int n    = row - b * NN;

    // ---- vectorized init: 4104 words = 1026 uint4 ----
    uint4 z; z.x = z.y = z.z = z.w = 0u;
    ((uint4*)sF)[t]       = z;
    ((uint4*)sF)[t + T1]  = z;
    if (t < 2) ((uint4*)sF)[1024 + t] = z;
    __syncthreads();

    // ---- load 4 elements, ordered keys, histogram ----
    const float4* nrow = (const float4*)(noise + (size_t)row * DD);
    const float4* xrow = (const float4*)(x + (size_t)b * DD);
    float4 nv = nrow[t];
    float4 xv = xrow[t];
    // match numpy: separate rounded mul and add (no FMA contraction)
    float v0 = __fadd_rn(xv.x, __fmul_rn(nv.x, SIG));
    float v1 = __fadd_rn(xv.y, __fmul_rn(nv.y, SIG));
    float v2 = __fadd_rn(xv.z, __fmul_rn(nv.z, SIG));
    float v3 = __fadd_rn(xv.w, __fmul_rn(nv.w, SIG));
    uint32_t u[4];
    {
        uint32_t ub;
        // order-preserving map: u = ub ^ (asr31(ub) | 0x80000000)  (2 VALU ops)
        ub = __float_as_uint(v0); u[0] = ub ^ (uint32_t)(((int32_t)ub >> 31) | (int32_t)0x80000000);
        ub = __float_as_uint(v1); u[1] = ub ^ (uint32_t)(((int32_t)ub >> 31) | (int32_t)0x80000000);
        ub = __float_as_uint(v2); u[2] = ub ^ (uint32_t)(((int32_t)ub >> 31) | (int32_t)0x80000000);
        ub = __float_as_uint(v3); u[3] = ub ^ (uint32_t)(((int32_t)ub >> 31) | (int32_t)0x80000000);
    }
    #pragma unroll
    for (int i = 0; i < 4; ++i) atomicAdd(&sF[u[i] >> 20], 1u);
    __syncthreads();

    // ---- suffix counts F(b): thread owns buckets [8t, 8t+8) ----
    uint4 ha = ((const uint4*)sF)[2 * t];
    uint4 hb = ((const uint4*)sF)[2 * t + 1];
    uint32_t h[8] = { ha.x, ha.y, ha.z, ha.w, hb.x, hb.y, hb.z, hb.w };
    uint32_t csum = h[0] + h[1] + h[2] + h[3] + h[4] + h[5] + h[6] + h[7];

    // wave-level inclusive suffix scan (higher lane = higher buckets)
    uint32_t s = csum;
    #pragma unroll
    for (int ofs = 1; ofs < 64; ofs <<= 1) {
        uint32_t o = __shfl_down(s, ofs, 64);
        s += (lane + ofs < 64) ? o : 0u;
    }
    if (lane == 0) sWS[w] = s;
    __syncthreads();
    if (t == 0) {                 // exclusive suffix over 8 wave totals
        uint32_t run = 0;
        #pragma unroll
        for (int i = 7; i >= 0; --i) { uint32_t tmp = sWS[i]; sWS[i] = run; run += tmp; }
    }
    __syncthreads();

    uint32_t above = sWS[w] + (s - csum);       // F(8t+8)
    uint32_t F[9];
    F[8] = above;
    #pragma unroll
    for (int i = 7; i >= 0; --i) F[i] = F[i + 1] + h[i];

    uint4 fa, fb;
    fa.x = F[0]; fa.y = F[1]; fa.z = F[2]; fa.w = F[3];
    fb.x = F[4]; fb.y = F[5]; fb.z = F[6]; fb.w = F[7];
    ((uint4*)sF)[2 * t]     = fa;
    ((uint4*)sF)[2 * t + 1] = fb;

    // crossing bucket b*: F(b*) >= K > F(b*+1); exactly one thread finds it
    #pragma unroll
    for (int i = 0; i < 8; ++i)
        if (F[i] >= KK && F[i + 1] < KK) { sC = F[i]; sBstar = (uint32_t)(8 * t + i); }
    __syncthreads();

    // ---- compact candidates (bucket >= b*); atomicAdd on sF[bk+1] allocates
    //      slots and leaves sF[bk+1] == F(bk) for every bucket >= b* ----
    // key: high 32 = ordered value, low 16 = (2047-d) so ties rank lower d first
    const uint32_t bstar = sBstar;
    #pragma unroll
    for (int i = 0; i < 4; ++i) {
        uint32_t bk = u[i] >> 20;
        if (bk >= bstar) {
            uint32_t pos = atomicAdd(&sF[bk + 1], 1u);
            int d = 4 * t + i;
            sCand[pos] = ((unsigned long long)u[i] << 16) |
                         (unsigned long long)(DD - 1 - d);
        }
    }
    __syncthreads();

    // ---- exact rank within candidate set ----
    // post-compaction: sF[bk+1] = F(bk) (hi), sF[bk+2] = F(bk+1) (lo)
    const int C = (int)sC;
    for (int p = t; p < C; p += T1) {
        unsigned long long key = sCand[p];
        int bkk = (int)(key >> 36);
        int hi  = (int)sF[bkk + 1];
        int lo  = (int)sF[bkk + 2];
        int rank = lo;
        for (int j = lo; j < hi; ++j)
            rank += (sCand[j] > key) ? 1 : 0;
        if (rank < KK)
            sIdx[rank] = (uint16_t)(DD - 1 - (int)(key & 0xFFFFull));
    }
    __syncthreads();

    // ---- scattered transposed store: idxT[(b*K + rank)*N + n] = d ----
    // 2-byte stores, fire-and-forget; makes K2's reads fully coalesced.
    if (t < KK)
        idxT[((size_t)(b * KK + t)) * NN + n] = sIdx[t];
}

// ---------------- Kernel 2: accumulate indicators, dense write, no atomics --
// One block = one (b,k) pair: 4096 blocks x 128 threads, 4 KB LDS histogram.
// Reads its 1000 indices as 125 contiguous uint4 (L2-resident), run-length
// aggregates before LDS atomics (rank-k index is stable across n, so naive
// atomics would serialize ~1000-deep for small k), writes out[b][k][:] dense.
#define T2 128
__global__ __launch_bounds__(T2, 8) void ptopk_accum(
    const uint16_t* __restrict__ idxT,
    float* __restrict__ out)
{
    __shared__ __align__(16) uint32_t hist[DD / 2];   // 1024 words = 4 KB

    const int t   = threadIdx.x;
    const int bkx = blockIdx.x;          // = b*KK + k

    uint4 z; z.x = z.y = z.z = z.w = 0u;
    ((uint4*)hist)[t]       = z;
    ((uint4*)hist)[t + T2]  = z;
    __syncthreads();

    // 1000 uint16 = 125 uint4 per (b,k) row, contiguous
    if (t < 125) {
        uint4 v = ((const uint4*)(idxT + (size_t)bkx * NN))[t];
        uint16_t d[8];
        d[0] = (uint16_t)(v.x & 0xFFFFu); d[1] = (uint16_t)(v.x >> 16);
        d[2] = (uint16_t)(v.y & 0xFFFFu); d[3] = (uint16_t)(v.y >> 16);
        d[4] = (uint16_t)(v.z & 0xFFFFu); d[5] = (uint16_t)(v.z >> 16);
        d[6] = (uint16_t)(v.w & 0xFFFFu); d[7] = (uint16_t)(v.w >> 16);
        // run-length aggregate consecutive equal indices -> one atomic per run
        uint16_t cur = d[0];
        uint32_t run = 1;
        #pragma unroll
        for (int i = 1; i < 8; ++i) {
            if (d[i] == cur) { run++; }
            else {
                atomicAdd(&hist[cur >> 1], run << ((cur & 1) << 4));
                cur = d[i]; run = 1;
            }
        }
        atomicAdd(&hist[cur >> 1], run << ((cur & 1) << 4));
    }
    __syncthreads();

    // dense coalesced write: 2048 floats; each thread 2 uint4 -> 4 float4
    float4* out4 = (float4*)(out + (size_t)bkx * DD);
    #pragma unroll
    for (int i = 0; i < 2; ++i) {
        int j = i * T2 + t;
        uint4 wv = ((const uint4*)hist)[j];
        float4 f0, f1;
        f0.x = (float)(wv.x & 0xFFFFu) * INVN;  f0.y = (float)(wv.x >> 16) * INVN;
        f0.z = (float)(wv.y & 0xFFFFu) * INVN;  f0.w = (float)(wv.y >> 16) * INVN;
        f1.x = (float)(wv.z & 0xFFFFu) * INVN;  f1.y = (float)(wv.z >> 16) * INVN;
        f1.z = (float)(wv.w & 0xFFFFu) * INVN;  f1.w = (float)(wv.w >> 16) * INVN;
        out4[2 * j]     = f0;
        out4[2 * j + 1] = f1;
    }
}

extern "C" void kernel_launch(void* const* d_in, const int* in_sizes, int n_in,
                              void* d_out, int out_size, void* d_ws, size_t ws_size,
                              hipStream_t stream) {
    const float* x     = (const float*)d_in[0];
    const float* noise = (const float*)d_in[1];
    float* out         = (float*)d_out;
    uint16_t* idxT     = (uint16_t*)d_ws;    // BB*KK*NN*2 = 8.2 MB, transposed

    hipLaunchKernelGGL(ptopk_rank,
                       dim3(BB * NN), dim3(T1), 0, stream,
                       x, noise, idxT);
    hipLaunchKernelGGL(ptopk_accum,
                       dim3(BB * KK), dim3(T2), 0, stream,
                       idxT, out);
}